// Round 1
// baseline (1245.273 us; speedup 1.0000x reference)
//
#include <hip/hip_runtime.h>
#include <hip/hip_fp16.h>
#include <stdint.h>

#define D_IN   768
#define D_SAE  12288
#define BATCH  8192
#define K_TOP  64
#define CAND_MAX 256

typedef _Float16 f16;
typedef _Float16 v8h __attribute__((ext_vector_type(8)));
typedef float v4f __attribute__((ext_vector_type(4)));

// async global->LDS, 16B/lane, wave-uniform LDS base (lane writes base + lane*16B)
__device__ inline void async16(const void* g, void* l) {
    __builtin_amdgcn_global_load_lds(
        (const __attribute__((address_space(1))) unsigned int*)g,
        (__attribute__((address_space(3))) unsigned int*)l, 16, 0, 0);
}

// ---------------- convert x: (x - b_dec) -> f16 hi/lo planes [BATCH][D_IN] ----------------
__global__ __launch_bounds__(256) void k_convert_x(
    const float* __restrict__ x, const float* __restrict__ b_dec,
    f16* __restrict__ xhi, f16* __restrict__ xlo)
{
    int i4 = (blockIdx.x * 256 + threadIdx.x) * 4;
    float4 v = *(const float4*)(x + i4);
    int col = i4 % D_IN;
    float vv[4] = { v.x - b_dec[col], v.y - b_dec[col + 1],
                    v.z - b_dec[col + 2], v.w - b_dec[col + 3] };
    union { short4 s; f16 h[4]; } H, L;
#pragma unroll
    for (int u = 0; u < 4; ++u) {
        H.h[u] = (f16)vv[u];
        L.h[u] = (f16)(vv[u] - (float)H.h[u]);
    }
    *(short4*)(xhi + i4) = H.s;
    *(short4*)(xlo + i4) = L.s;
}

// ---------------- convert+transpose W_enc [D_IN][D_SAE] -> hi/lo planes [D_SAE][D_IN] ----------------
__global__ __launch_bounds__(256) void k_convert_wt(
    const float* __restrict__ W, f16* __restrict__ whiT, f16* __restrict__ wloT)
{
    __shared__ float tile[32][33];
    const int n0 = blockIdx.x * 32;
    const int k0 = blockIdx.y * 32;
    const int c = threadIdx.x & 31;
    const int rr = threadIdx.x >> 5;   // 0..7
#pragma unroll
    for (int s = 0; s < 4; ++s) {
        int r = s * 8 + rr;
        tile[r][c] = W[(size_t)(k0 + r) * D_SAE + n0 + c];
    }
    __syncthreads();
#pragma unroll
    for (int s = 0; s < 4; ++s) {
        int r2 = s * 8 + rr;                 // n within tile
        float v = tile[c][r2];               // W[k0+c][n0+r2]
        f16 hi = (f16)v;
        f16 lo = (f16)(v - (float)hi);
        whiT[(size_t)(n0 + r2) * D_IN + k0 + c] = hi;
        wloT[(size_t)(n0 + r2) * D_IN + k0 + c] = lo;
    }
}

// ---------------- approximate encode GEMM (f16 MFMA, 128x128 tile, BK=64) ----------------
// Writes relu(A*Bt^T + b_enc) rounded to f16 (nontemporal) into the FIRST HALF
// of each row's fp32 span in the sparse output region.
__global__ __launch_bounds__(256) void k_gemm_f16(
    const f16* __restrict__ A,    // Xhi [BATCH][D_IN]
    const f16* __restrict__ Bt,   // WhiT [D_SAE][D_IN]
    const float* __restrict__ b_enc,
    f16* __restrict__ outap)
{
    __shared__ f16 Asm[2][128 * 32];
    __shared__ f16 Bsm[2][128 * 32];
    const int tid  = threadIdx.x;
    const int wave = tid >> 6;
    const int lane = tid & 63;
    const int bn = blockIdx.x * 128;
    const int bm = blockIdx.y * 128;

    const int r16  = lane >> 2;       // 0..15 staging row
    const int kc8  = (lane & 3) * 8;  // f16 k-offset within 32
    const int mrow = lane & 15;
    const int quad = lane >> 4;
    const int wm = (wave & 1) * 64;
    const int wn = (wave >> 1) * 64;

    v4f acc[4][4] = {};

    const f16* gA = A  + (size_t)(bm + wave * 32 + r16) * D_IN + kc8;
    const f16* gB = Bt + (size_t)(bn + wave * 32 + r16) * D_IN + kc8;
    f16* lA0  = &Asm[0][(wave * 32) * 32];
    f16* lA0b = &Asm[0][(wave * 32 + 16) * 32];
    f16* lB0  = &Bsm[0][(wave * 32) * 32];
    f16* lB0b = &Bsm[0][(wave * 32 + 16) * 32];
    f16* lA1  = &Asm[1][(wave * 32) * 32];
    f16* lA1b = &Asm[1][(wave * 32 + 16) * 32];
    f16* lB1  = &Bsm[1][(wave * 32) * 32];
    f16* lB1b = &Bsm[1][(wave * 32 + 16) * 32];

    for (int k0 = 0; k0 < D_IN; k0 += 64) {
        __syncthreads();
        async16(gA + k0,               lA0);
        async16(gA + k0 + 16 * D_IN,   lA0b);
        async16(gB + k0,               lB0);
        async16(gB + k0 + 16 * D_IN,   lB0b);
        async16(gA + k0 + 32,              lA1);
        async16(gA + k0 + 32 + 16 * D_IN,  lA1b);
        async16(gB + k0 + 32,              lB1);
        async16(gB + k0 + 32 + 16 * D_IN,  lB1b);
        __syncthreads();

#pragma unroll
        for (int s = 0; s < 2; ++s) {
            v8h af[4], bf[4];
#pragma unroll
            for (int i = 0; i < 4; ++i)
                af[i] = *(const v8h*)&Asm[s][(wm + i * 16 + mrow) * 32 + quad * 8];
#pragma unroll
            for (int j = 0; j < 4; ++j)
                bf[j] = *(const v8h*)&Bsm[s][(wn + j * 16 + mrow) * 32 + quad * 8];
#pragma unroll
            for (int i = 0; i < 4; ++i)
#pragma unroll
                for (int j = 0; j < 4; ++j)
                    acc[i][j] = __builtin_amdgcn_mfma_f32_16x16x32_f16(af[i], bf[j], acc[i][j], 0, 0, 0);
        }
    }

#pragma unroll
    for (int i = 0; i < 4; ++i) {
#pragma unroll
        for (int r = 0; r < 4; ++r) {
            int grow = bm + wm + i * 16 + quad * 4 + r;
            f16* op = outap + (size_t)grow * (2 * D_SAE) + bn + wn;
#pragma unroll
            for (int j = 0; j < 4; ++j) {
                int c = j * 16 + mrow;
                float val = acc[i][j][r] + b_enc[bn + wn + c];
                __builtin_nontemporal_store((f16)(val > 0.f ? val : 0.f), op + c);
            }
        }
    }
}

// 256-bin suffix scan via wave shfl + 4-wave LDS combine. 2 barriers (internal 1;
// caller provides separation between successive calls). Returns inclusive suffix
// at bin t; *tot_out = total count.
__device__ __forceinline__ unsigned suffix_scan_256(unsigned h, int t, unsigned* wtot, unsigned* tot_out) {
    const int lane = t & 63;
    const int w = t >> 6;
    unsigned s = h;
#pragma unroll
    for (int off = 1; off < 64; off <<= 1) {
        unsigned o = __shfl_down(s, off);
        if (lane + off < 64) s += o;
    }
    if (lane == 0) wtot[w] = s;
    __syncthreads();
    unsigned suf = s;
    unsigned tot = 0;
#pragma unroll
    for (int w2 = 0; w2 < 4; ++w2) {
        tot += wtot[w2];
        if (w2 > w) suf += wtot[w2];
    }
    *tot_out = tot;
    return suf;
}

// ---------------- per-row: cutoff/compaction + sequential exact recompute + scatter + decode ----------------
__global__ __launch_bounds__(256) void k_topk2(
    float* __restrict__ sparse,        // [BATCH][D_SAE]: in f16 approx (first half), out final sparse_acts
    const f16* __restrict__ Xhi, const f16* __restrict__ Xlo,
    const f16* __restrict__ WhiT, const f16* __restrict__ WloT,
    const float* __restrict__ b_enc,
    const float* __restrict__ Wdec,    // [D_SAE][D_IN]
    const float* __restrict__ b_dec,
    float* __restrict__ recon)         // [BATCH][D_IN]
{
    const int row = blockIdx.x;
    const int t = threadIdx.x;
    const int lane = t & 63;
    float* rp = sparse + (size_t)row * D_SAE;
    const f16* ap = (const f16*)rp;

    // ---- load f16 approx row, 48 per thread, coalesced 16B, nontemporal ----
    v8h av[6];
#pragma unroll
    for (int j = 0; j < 6; ++j)
        av[j] = __builtin_nontemporal_load((const v8h*)(ap + ((size_t)j * 256 + t) * 8));

    // Row lives in registers now. Order the aliased load->store explicitly, then
    // issue the 48 KB zero-fill IMMEDIATELY so the 402 MB of fleet-wide writes
    // drain in the background under the select/recompute/ranking phases.
    // (Every subsequent __syncthreads drains vmcnt, so zeros land before scatter.)
    asm volatile("s_waitcnt vmcnt(0)" ::: "memory");
#pragma unroll
    for (int j = 0; j < 12; ++j) {
        v4f z = {0.f, 0.f, 0.f, 0.f};
        __builtin_nontemporal_store(z, (v4f*)(rp + ((size_t)j * 256 + t) * 4));
    }

    __shared__ unsigned hist[256];
    __shared__ unsigned wtot[4];
    __shared__ float sh_cutoff;
    __shared__ int sh_ncand;
    __shared__ int   cand_i[CAND_MAX];
    __shared__ float cand_v[CAND_MAX];
    __shared__ float kept_v[K_TOP];
    __shared__ int   kept_i[K_TOP];
    __shared__ float xr[D_IN];

    const float margin = 0.05f;

    hist[t] = 0;
    if (t == 0) sh_ncand = 0;
    // overlap: exact x row (hi+lo) into LDS for the recompute phase
    for (int k = t; k < D_IN; k += 256)
        xr[k] = (float)Xhi[(size_t)row * D_IN + k] + (float)Xlo[(size_t)row * D_IN + k];
    __syncthreads();

    // ---- level 0: histogram over [2.0, 10.0), 1/32 bins. Top-64/12288 cutoff sits
    // near 3.6 for this problem's statistics (pre_acts ~ N(0,1.41^2); count(x>=2)
    // ~ 960 >> 64), so only ~8% of elements take the atomic. Pathological rows
    // fall back to the original proven [0.25,8.25) / (0,0.25) ladder below. ----
#pragma unroll
    for (int j = 0; j < 6; ++j)
#pragma unroll
        for (int u = 0; u < 8; ++u) {
            float x = (float)av[j][u];
            if (x >= 2.0f) {
                int b = (int)((x - 2.0f) * 32.0f); if (b > 255) b = 255;
                atomicAdd(&hist[b], 1u);
            }
        }
    __syncthreads();
    unsigned h0 = hist[t];
    unsigned tot0;
    unsigned suf0 = suffix_scan_256(h0, t, wtot, &tot0);
    if (tot0 >= K_TOP) {
        // crossing: suf[t] >= K && suf[t+1] < K, with suf[t+1] == suf[t]-h[t]
        if (suf0 >= K_TOP && suf0 - h0 < K_TOP)
            sh_cutoff = fmaxf(2.0f + (float)t * (1.0f / 32.0f) - margin, 1e-30f);
    }
    __syncthreads();
    if (tot0 < K_TOP) {
        // ---- level 1: [0.25, 8.25), 1/32 bins (original proven range) ----
        hist[t] = 0;
        __syncthreads();
#pragma unroll
        for (int j = 0; j < 6; ++j)
#pragma unroll
            for (int u = 0; u < 8; ++u) {
                float x = (float)av[j][u];
                if (x >= 0.25f) {
                    int b = (int)(x * 32.0f); if (b > 255) b = 255;
                    atomicAdd(&hist[b], 1u);
                }
            }
        __syncthreads();
        unsigned h1 = hist[t];
        unsigned tot1;
        unsigned suf1 = suffix_scan_256(h1, t, wtot, &tot1);
        if (tot1 >= K_TOP) {
            if (suf1 >= K_TOP && suf1 - h1 < K_TOP)
                sh_cutoff = fmaxf((float)t * (1.0f / 32.0f) - margin, 1e-30f);
        }
        __syncthreads();
        if (tot1 < K_TOP) {
            // ---- level 2: refine (0, 0.25) ----
            hist[t] = 0;
            __syncthreads();
#pragma unroll
            for (int j = 0; j < 6; ++j)
#pragma unroll
                for (int u = 0; u < 8; ++u) {
                    float x = (float)av[j][u];
                    if (x > 0.0f && x < 0.25f) {
                        int b = (int)(x * 1024.0f); if (b > 255) b = 255;
                        atomicAdd(&hist[b], 1u);
                    }
                }
            __syncthreads();
            unsigned h2 = hist[t];
            unsigned tot2;
            unsigned suf2 = suffix_scan_256(h2, t, wtot, &tot2);
            unsigned need = K_TOP - tot1;
            if (tot2 >= need) {
                if (suf2 >= need && suf2 - h2 < need)
                    sh_cutoff = fmaxf((float)t * (1.0f / 1024.0f) - margin, 1e-30f);
            } else {
                if (t == 0) sh_cutoff = 1e-30f;  // fewer than K positives: keep all positives
            }
        }
    }
    __syncthreads();
    const float cutoff = sh_cutoff;

    // ---- collect candidate indices: ballot + prefix-popcount, one LDS atomic
    //      per wave per passing chunk (replaces ~100 serialized single-address
    //      atomics). Order is deterministic; ranking below is order-independent. ----
#pragma unroll
    for (int j = 0; j < 6; ++j)
#pragma unroll
        for (int u = 0; u < 8; ++u) {
            float x = (float)av[j][u];
            bool pass = (x >= cutoff);
            unsigned long long m = __ballot(pass);
            if (m != 0ull) {
                int leader = (int)__builtin_ctzll(m);
                int cnt = (int)__builtin_popcountll(m);
                int base0 = 0;
                if (lane == leader) base0 = atomicAdd(&sh_ncand, cnt);
                base0 = __shfl(base0, leader);
                if (pass) {
                    int pos = base0 + (int)__builtin_popcountll(m & ((1ull << lane) - 1ull));
                    if (pos < CAND_MAX) { cand_i[pos] = (j * 256 + t) * 8 + u; cand_v[pos] = x; }
                }
            }
        }
    __syncthreads();
    int ncand = sh_ncand; if (ncand > CAND_MAX) ncand = CAND_MAX;

    // ---- exact recompute: SEQUENTIAL k per thread — rounding correlated with
    //      the np reference; DO NOT parallelize or reorder this sum ----
    for (int c = t; c < ncand; c += 256) {
        const f16* wh = WhiT + (size_t)cand_i[c] * D_IN;
        const f16* wl = WloT + (size_t)cand_i[c] * D_IN;
        float acc = 0.f;
        for (int k = 0; k < D_IN; k += 8) {
            v8h hv = *(const v8h*)(wh + k);
            v8h lv = *(const v8h*)(wl + k);
#pragma unroll
            for (int u = 0; u < 8; ++u)
                acc += xr[k + u] * ((float)hv[u] + (float)lv[u]);
        }
        acc += b_enc[cand_i[c]];
        cand_v[c] = acc > 0.f ? acc : 0.f;
    }
    __syncthreads();

    // ---- exact ranking (value desc, index asc), rank-indexed kept store ----
    for (int c = t; c < ncand; c += 256) {
        float vc = cand_v[c]; int ic = cand_i[c];
        int r = 0;
        for (int m = 0; m < ncand; ++m) {
            float vm = cand_v[m];
            r += (vm > vc || (vm == vc && cand_i[m] < ic)) ? 1 : 0;
        }
        if (r < K_TOP) { kept_v[r] = vc; kept_i[r] = ic; }
    }
    __syncthreads();   // also drains vmcnt: the early zero-fill is complete here
    int nk = ncand < K_TOP ? ncand : K_TOP;

    // ---- scatter exact values over the (already-zeroed) row ----
    if (t < nk) rp[kept_i[t]] = kept_v[t];

    // ---- sparse decode: recon = sum kept_v * Wdec[kept_i,:] + b_dec ----
    float r0 = b_dec[t], r1 = b_dec[t + 256], r2 = b_dec[t + 512];
#pragma unroll 4
    for (int m = 0; m < nk; ++m) {
        float val = kept_v[m];
        const float* wr = Wdec + (size_t)kept_i[m] * D_IN;
        r0 += val * wr[t];
        r1 += val * wr[t + 256];
        r2 += val * wr[t + 512];
    }
    float* rc = recon + (size_t)row * D_IN;
    __builtin_nontemporal_store(r0, rc + t);
    __builtin_nontemporal_store(r1, rc + t + 256);
    __builtin_nontemporal_store(r2, rc + t + 512);
}

extern "C" void kernel_launch(void* const* d_in, const int* in_sizes, int n_in,
                              void* d_out, int out_size, void* d_ws, size_t ws_size,
                              hipStream_t stream) {
    const float* x     = (const float*)d_in[0];
    const float* W_enc = (const float*)d_in[1];
    const float* b_enc = (const float*)d_in[2];
    const float* W_dec = (const float*)d_in[3];
    const float* b_dec = (const float*)d_in[4];
    float* out    = (float*)d_out;
    float* recon  = out;                             // [BATCH][D_IN]
    float* sparse = out + (size_t)BATCH * D_IN;      // [BATCH][D_SAE]

    const size_t xplane = (size_t)BATCH * D_IN;      // 6291456
    const size_t wplane = (size_t)D_SAE * D_IN;      // 9437184
    f16* xhi  = (f16*)d_ws;
    f16* xlo  = xhi + xplane;
    f16* whiT = xlo + xplane;
    f16* wloT = whiT + wplane;

    k_convert_x<<<xplane / 1024, 256, 0, stream>>>(x, b_dec, xhi, xlo);
    k_convert_wt<<<dim3(D_SAE / 32, D_IN / 32), 256, 0, stream>>>(W_enc, whiT, wloT);
    k_gemm_f16<<<dim3(D_SAE / 128, BATCH / 128), 256, 0, stream>>>(xhi, whiT, b_enc, (f16*)sparse);
    k_topk2<<<BATCH, 256, 0, stream>>>(sparse, xhi, xlo, whiT, wloT, b_enc, W_dec, b_dec, recon);
}

// Round 2
// 1210.363 us; speedup vs baseline: 1.0288x; 1.0288x over previous
//
#include <hip/hip_runtime.h>
#include <hip/hip_fp16.h>
#include <stdint.h>

#define D_IN   768
#define D_SAE  12288
#define BATCH  8192
#define K_TOP  64
#define CAND_MAX 256

typedef _Float16 f16;
typedef _Float16 v8h __attribute__((ext_vector_type(8)));
typedef float v4f __attribute__((ext_vector_type(4)));

// async global->LDS, 16B/lane, wave-uniform LDS base (lane writes base + lane*16B)
__device__ inline void async16(const void* g, void* l) {
    __builtin_amdgcn_global_load_lds(
        (const __attribute__((address_space(1))) unsigned int*)g,
        (__attribute__((address_space(3))) unsigned int*)l, 16, 0, 0);
}

// ---------------- convert x: (x - b_dec) -> f16 hi plane [BATCH][D_IN] ----------------
__global__ __launch_bounds__(256) void k_convert_x(
    const float* __restrict__ x, const float* __restrict__ b_dec,
    f16* __restrict__ xhi)
{
    int i4 = (blockIdx.x * 256 + threadIdx.x) * 4;
    float4 v = *(const float4*)(x + i4);
    int col = i4 % D_IN;
    float vv[4] = { v.x - b_dec[col], v.y - b_dec[col + 1],
                    v.z - b_dec[col + 2], v.w - b_dec[col + 3] };
    union { short4 s; f16 h[4]; } H;
#pragma unroll
    for (int u = 0; u < 4; ++u) H.h[u] = (f16)vv[u];
    *(short4*)(xhi + i4) = H.s;
}

// ---------------- convert+transpose W_enc [D_IN][D_SAE] -> hi/lo planes [D_SAE][D_IN] ----------------
__global__ __launch_bounds__(256) void k_convert_wt(
    const float* __restrict__ W, f16* __restrict__ whiT, f16* __restrict__ wloT)
{
    __shared__ float tile[32][33];
    const int n0 = blockIdx.x * 32;
    const int k0 = blockIdx.y * 32;
    const int c = threadIdx.x & 31;
    const int rr = threadIdx.x >> 5;   // 0..7
#pragma unroll
    for (int s = 0; s < 4; ++s) {
        int r = s * 8 + rr;
        tile[r][c] = W[(size_t)(k0 + r) * D_SAE + n0 + c];
    }
    __syncthreads();
#pragma unroll
    for (int s = 0; s < 4; ++s) {
        int r2 = s * 8 + rr;                 // n within tile
        float v = tile[c][r2];               // W[k0+c][n0+r2]
        f16 hi = (f16)v;
        f16 lo = (f16)(v - (float)hi);
        whiT[(size_t)(n0 + r2) * D_IN + k0 + c] = hi;
        wloT[(size_t)(n0 + r2) * D_IN + k0 + c] = lo;
    }
}

// ---------------- convert W_dec [D_SAE][D_IN] fp32 -> f16 (decode is tolerant:
// per-term err <= val*|w|*2^-12, RMS over 64 terms ~2e-4 on recon) ----------------
__global__ __launch_bounds__(256) void k_convert_wd(
    const float* __restrict__ W, f16* __restrict__ Wh)
{
    int i4 = (blockIdx.x * 256 + threadIdx.x) * 4;
    float4 v = *(const float4*)(W + i4);
    union { short4 s; f16 h[4]; } H;
    H.h[0] = (f16)v.x; H.h[1] = (f16)v.y; H.h[2] = (f16)v.z; H.h[3] = (f16)v.w;
    *(short4*)(Wh + i4) = H.s;
}

// ---------------- approximate encode GEMM (f16 MFMA, 128x128 tile) ----------------
// T3-minimal 2-phase: BK=32 double-buffered in the SAME 32 KB LDS footprint;
// next chunk's global_load_lds issued BEFORE compute so staging latency hides
// under 16 MFMA + 8 ds_read_b128. One barrier per chunk (it drains vmcnt for the
// chunk staged last iteration and lgkmcnt for this buffer's readers).
__global__ __launch_bounds__(256) void k_gemm_f16(
    const f16* __restrict__ A,    // Xhi [BATCH][D_IN]
    const f16* __restrict__ Bt,   // WhiT [D_SAE][D_IN]
    const float* __restrict__ b_enc,
    f16* __restrict__ outap)
{
    __shared__ f16 Asm[2][128 * 32];
    __shared__ f16 Bsm[2][128 * 32];
    const int tid  = threadIdx.x;
    const int wave = tid >> 6;
    const int lane = tid & 63;
    const int bn = blockIdx.x * 128;
    const int bm = blockIdx.y * 128;

    const int r16  = lane >> 2;       // 0..15 staging row
    const int kc8  = (lane & 3) * 8;  // f16 k-offset within 32
    const int mrow = lane & 15;
    const int quad = lane >> 4;
    const int wm = (wave & 1) * 64;
    const int wn = (wave >> 1) * 64;

    v4f acc[4][4] = {};

    const f16* gA = A  + (size_t)(bm + wave * 32 + r16) * D_IN + kc8;
    const f16* gB = Bt + (size_t)(bn + wave * 32 + r16) * D_IN + kc8;
    f16* lA[2] = { &Asm[0][(wave * 32) * 32], &Asm[1][(wave * 32) * 32] };
    f16* lB[2] = { &Bsm[0][(wave * 32) * 32], &Bsm[1][(wave * 32) * 32] };

    // stage one 128x32 A-chunk + 128x32 B-chunk (16 KB) at f16 k-offset kk into buffer b
    #define STAGE(b, kk)                                   \
        do {                                               \
            async16(gA + (kk),            lA[b]);          \
            async16(gA + (kk) + 16*D_IN,  lA[b] + 16*32);  \
            async16(gB + (kk),            lB[b]);          \
            async16(gB + (kk) + 16*D_IN,  lB[b] + 16*32);  \
        } while (0)

    STAGE(0, 0);
#pragma unroll 2
    for (int it = 0; it < 24; ++it) {
        const int cur = it & 1;           // unroll-2 makes this compile-time
        __syncthreads();                  // buf[cur] staged; prev readers of buf[cur^1] done
        if (it + 1 < 24) STAGE(cur ^ 1, (it + 1) * 32);
        v8h af[4], bf[4];
#pragma unroll
        for (int i = 0; i < 4; ++i)
            af[i] = *(const v8h*)&Asm[cur][(wm + i * 16 + mrow) * 32 + quad * 8];
#pragma unroll
        for (int j = 0; j < 4; ++j)
            bf[j] = *(const v8h*)&Bsm[cur][(wn + j * 16 + mrow) * 32 + quad * 8];
#pragma unroll
        for (int i = 0; i < 4; ++i)
#pragma unroll
            for (int j = 0; j < 4; ++j)
                acc[i][j] = __builtin_amdgcn_mfma_f32_16x16x32_f16(af[i], bf[j], acc[i][j], 0, 0, 0);
    }
    #undef STAGE

#pragma unroll
    for (int i = 0; i < 4; ++i) {
#pragma unroll
        for (int r = 0; r < 4; ++r) {
            int grow = bm + wm + i * 16 + quad * 4 + r;
            f16* op = outap + (size_t)grow * (2 * D_SAE) + bn + wn;
#pragma unroll
            for (int j = 0; j < 4; ++j) {
                int c = j * 16 + mrow;
                float val = acc[i][j][r] + b_enc[bn + wn + c];
                __builtin_nontemporal_store((f16)(val > 0.f ? val : 0.f), op + c);
            }
        }
    }
}

// 256-bin suffix scan via wave shfl + 4-wave LDS combine. Returns inclusive suffix
// at bin t; *tot_out = total count.
__device__ __forceinline__ unsigned suffix_scan_256(unsigned h, int t, unsigned* wtot, unsigned* tot_out) {
    const int lane = t & 63;
    const int w = t >> 6;
    unsigned s = h;
#pragma unroll
    for (int off = 1; off < 64; off <<= 1) {
        unsigned o = __shfl_down(s, off);
        if (lane + off < 64) s += o;
    }
    if (lane == 0) wtot[w] = s;
    __syncthreads();
    unsigned suf = s;
    unsigned tot = 0;
#pragma unroll
    for (int w2 = 0; w2 < 4; ++w2) {
        tot += wtot[w2];
        if (w2 > w) suf += wtot[w2];
    }
    *tot_out = tot;
    return suf;
}

// ---------------- per-row: cutoff/compaction + sequential exact recompute + scatter + decode ----------------
__global__ __launch_bounds__(256) void k_topk2(
    float* __restrict__ sparse,        // [BATCH][D_SAE]: in f16 approx (first half), out final sparse_acts
    const float* __restrict__ x,       // original fp32 [BATCH][D_IN]
    const f16* __restrict__ WhiT, const f16* __restrict__ WloT,
    const float* __restrict__ b_enc,
    const f16* __restrict__ Wdh,       // f16 W_dec [D_SAE][D_IN]
    const float* __restrict__ b_dec,
    float* __restrict__ recon)         // [BATCH][D_IN]
{
    const int row = blockIdx.x;
    const int t = threadIdx.x;
    const int lane = t & 63;
    float* rp = sparse + (size_t)row * D_SAE;
    const f16* ap = (const f16*)rp;

    // ---- load f16 approx row, 48 per thread, coalesced 16B, nontemporal ----
    v8h av[6];
#pragma unroll
    for (int j = 0; j < 6; ++j)
        av[j] = __builtin_nontemporal_load((const v8h*)(ap + ((size_t)j * 256 + t) * 8));

    __shared__ unsigned hist[256];
    __shared__ unsigned wtot[4];
    __shared__ float sh_cutoff;
    __shared__ int sh_ncand;
    __shared__ int   cand_i[CAND_MAX];
    __shared__ float cand_v[CAND_MAX];
    __shared__ float kept_v[K_TOP];
    __shared__ int   kept_i[K_TOP];
    __shared__ float xr[D_IN];

    const float margin = 0.05f;

    hist[t] = 0;
    if (t == 0) sh_ncand = 0;
    // overlap: exact x row (fp32, centered) into LDS for the recompute phase
    for (int k = t; k < D_IN; k += 256)
        xr[k] = x[(size_t)row * D_IN + k] - b_dec[k];
    __syncthreads();

    // ---- level 0: histogram over [2.0, 10.0), 1/32 bins. Top-64/12288 cutoff sits
    // near 3.6 for this problem's statistics; only ~8% of elements take the atomic.
    // Pathological rows fall back to the proven [0.25,8.25) / (0,0.25) ladder. ----
#pragma unroll
    for (int j = 0; j < 6; ++j)
#pragma unroll
        for (int u = 0; u < 8; ++u) {
            float x0 = (float)av[j][u];
            if (x0 >= 2.0f) {
                int b = (int)((x0 - 2.0f) * 32.0f); if (b > 255) b = 255;
                atomicAdd(&hist[b], 1u);
            }
        }
    __syncthreads();
    unsigned h0 = hist[t];
    unsigned tot0;
    unsigned suf0 = suffix_scan_256(h0, t, wtot, &tot0);
    if (tot0 >= K_TOP) {
        if (suf0 >= K_TOP && suf0 - h0 < K_TOP)
            sh_cutoff = fmaxf(2.0f + (float)t * (1.0f / 32.0f) - margin, 1e-30f);
    }
    __syncthreads();
    if (tot0 < K_TOP) {
        // ---- level 1: [0.25, 8.25), 1/32 bins (original proven range) ----
        hist[t] = 0;
        __syncthreads();
#pragma unroll
        for (int j = 0; j < 6; ++j)
#pragma unroll
            for (int u = 0; u < 8; ++u) {
                float x0 = (float)av[j][u];
                if (x0 >= 0.25f) {
                    int b = (int)(x0 * 32.0f); if (b > 255) b = 255;
                    atomicAdd(&hist[b], 1u);
                }
            }
        __syncthreads();
        unsigned h1 = hist[t];
        unsigned tot1;
        unsigned suf1 = suffix_scan_256(h1, t, wtot, &tot1);
        if (tot1 >= K_TOP) {
            if (suf1 >= K_TOP && suf1 - h1 < K_TOP)
                sh_cutoff = fmaxf((float)t * (1.0f / 32.0f) - margin, 1e-30f);
        }
        __syncthreads();
        if (tot1 < K_TOP) {
            // ---- level 2: refine (0, 0.25) ----
            hist[t] = 0;
            __syncthreads();
#pragma unroll
            for (int j = 0; j < 6; ++j)
#pragma unroll
                for (int u = 0; u < 8; ++u) {
                    float x0 = (float)av[j][u];
                    if (x0 > 0.0f && x0 < 0.25f) {
                        int b = (int)(x0 * 1024.0f); if (b > 255) b = 255;
                        atomicAdd(&hist[b], 1u);
                    }
                }
            __syncthreads();
            unsigned h2 = hist[t];
            unsigned tot2;
            unsigned suf2 = suffix_scan_256(h2, t, wtot, &tot2);
            unsigned need = K_TOP - tot1;
            if (tot2 >= need) {
                if (suf2 >= need && suf2 - h2 < need)
                    sh_cutoff = fmaxf((float)t * (1.0f / 1024.0f) - margin, 1e-30f);
            } else {
                if (t == 0) sh_cutoff = 1e-30f;  // fewer than K positives: keep all positives
            }
        }
    }
    __syncthreads();
    const float cutoff = sh_cutoff;

    // ---- collect candidate indices: ballot + prefix-popcount, one LDS atomic
    //      per wave per passing chunk. Ranking below is order-independent. ----
#pragma unroll
    for (int j = 0; j < 6; ++j)
#pragma unroll
        for (int u = 0; u < 8; ++u) {
            float x0 = (float)av[j][u];
            bool pass = (x0 >= cutoff);
            unsigned long long m = __ballot(pass);
            if (m != 0ull) {
                int leader = (int)__builtin_ctzll(m);
                int cnt = (int)__builtin_popcountll(m);
                int base0 = 0;
                if (lane == leader) base0 = atomicAdd(&sh_ncand, cnt);
                base0 = __shfl(base0, leader);
                if (pass) {
                    int pos = base0 + (int)__builtin_popcountll(m & ((1ull << lane) - 1ull));
                    if (pos < CAND_MAX) { cand_i[pos] = (j * 256 + t) * 8 + u; cand_v[pos] = x0; }
                }
            }
        }
    __syncthreads();
    int ncand = sh_ncand; if (ncand > CAND_MAX) ncand = CAND_MAX;

    // ---- exact recompute: SEQUENTIAL k per thread — rounding correlated with
    //      the np reference; DO NOT parallelize or reorder this sum ----
    for (int c = t; c < ncand; c += 256) {
        const f16* wh = WhiT + (size_t)cand_i[c] * D_IN;
        const f16* wl = WloT + (size_t)cand_i[c] * D_IN;
        float acc = 0.f;
        for (int k = 0; k < D_IN; k += 8) {
            v8h hv = *(const v8h*)(wh + k);
            v8h lv = *(const v8h*)(wl + k);
#pragma unroll
            for (int u = 0; u < 8; ++u)
                acc += xr[k + u] * ((float)hv[u] + (float)lv[u]);
        }
        acc += b_enc[cand_i[c]];
        cand_v[c] = acc > 0.f ? acc : 0.f;
    }
    __syncthreads();

    // ---- exact ranking (value desc, index asc), rank-indexed kept store ----
    for (int c = t; c < ncand; c += 256) {
        float vc = cand_v[c]; int ic = cand_i[c];
        int r = 0;
        for (int m = 0; m < ncand; ++m) {
            float vm = cand_v[m];
            r += (vm > vc || (vm == vc && cand_i[m] < ic)) ? 1 : 0;
        }
        if (r < K_TOP) { kept_v[r] = vc; kept_i[r] = ic; }
    }
    __syncthreads();
    int nk = ncand < K_TOP ? ncand : K_TOP;

    // ---- write sparse row: nontemporal zero-fill then scatter exact values ----
#pragma unroll
    for (int j = 0; j < 12; ++j) {
        v4f z = {0.f, 0.f, 0.f, 0.f};
        __builtin_nontemporal_store(z, (v4f*)(rp + ((size_t)j * 256 + t) * 4));
    }
    __syncthreads();
    if (t < nk) rp[kept_i[t]] = kept_v[t];

    // ---- sparse decode (f16 W_dec): recon = sum kept_v * Wdh[kept_i,:] + b_dec ----
    float r0 = b_dec[t], r1 = b_dec[t + 256], r2 = b_dec[t + 512];
#pragma unroll 4
    for (int m = 0; m < nk; ++m) {
        float val = kept_v[m];
        const f16* wr = Wdh + (size_t)kept_i[m] * D_IN;
        r0 += val * (float)wr[t];
        r1 += val * (float)wr[t + 256];
        r2 += val * (float)wr[t + 512];
    }
    float* rc = recon + (size_t)row * D_IN;
    __builtin_nontemporal_store(r0, rc + t);
    __builtin_nontemporal_store(r1, rc + t + 256);
    __builtin_nontemporal_store(r2, rc + t + 512);
}

extern "C" void kernel_launch(void* const* d_in, const int* in_sizes, int n_in,
                              void* d_out, int out_size, void* d_ws, size_t ws_size,
                              hipStream_t stream) {
    const float* x     = (const float*)d_in[0];
    const float* W_enc = (const float*)d_in[1];
    const float* b_enc = (const float*)d_in[2];
    const float* W_dec = (const float*)d_in[3];
    const float* b_dec = (const float*)d_in[4];
    float* out    = (float*)d_out;
    float* recon  = out;                             // [BATCH][D_IN]
    float* sparse = out + (size_t)BATCH * D_IN;      // [BATCH][D_SAE]

    const size_t xplane = (size_t)BATCH * D_IN;      // 6291456
    const size_t wplane = (size_t)D_SAE * D_IN;      // 9437184
    f16* xhi  = (f16*)d_ws;
    f16* whiT = xhi + xplane;
    f16* wloT = whiT + wplane;
    f16* wdh  = wloT + wplane;

    k_convert_x<<<xplane / 1024, 256, 0, stream>>>(x, b_dec, xhi);
    k_convert_wt<<<dim3(D_SAE / 32, D_IN / 32), 256, 0, stream>>>(W_enc, whiT, wloT);
    k_convert_wd<<<wplane / 1024, 256, 0, stream>>>(W_dec, wdh);
    k_gemm_f16<<<dim3(D_SAE / 128, BATCH / 128), 256, 0, stream>>>(xhi, whiT, b_enc, (f16*)sparse);
    k_topk2<<<BATCH, 256, 0, stream>>>(sparse, x, whiT, wloT, b_enc, wdh, b_dec, recon);
}